// Round 12
// baseline (38295.972 us; speedup 1.0000x reference)
//
#include <hip/hip_runtime.h>
#include <math.h>

#define DIMD 512
#define NSEQ 4096
#define NHEAD 8
#define HD 64
#define TOPK 16
#define LSTR 68   // LDS row stride (floats): 68*4B=272B, 16B-aligned, banks spread

// ---------------------------------------------------------------------------
// Per-row LayerNorm stats: mean and 1/sqrt(var+eps). One block per row.
// ---------------------------------------------------------------------------
__global__ __launch_bounds__(256) void ln_stats_kernel(
    const float* __restrict__ X, float2* __restrict__ S)
{
    int r = blockIdx.x;
    int t = threadIdx.x;
    const float* xr = X + (size_t)r * DIMD;
    float a = xr[t], b = xr[t + 256];
    float s = a + b;
    float sq = a * a + b * b;
    #pragma unroll
    for (int off = 32; off > 0; off >>= 1) {
        s  += __shfl_down(s, off, 64);
        sq += __shfl_down(sq, off, 64);
    }
    __shared__ float red[8];
    int wv = t >> 6, ln = t & 63;
    if (ln == 0) { red[wv] = s; red[wv + 4] = sq; }
    __syncthreads();
    if (t == 0) {
        float st  = red[0] + red[1] + red[2] + red[3];
        float sqt = red[4] + red[5] + red[6] + red[7];
        float mean = st * (1.0f / DIMD);
        float var  = sqt * (1.0f / DIMD) - mean * mean;
        float inv  = 1.0f / sqrtf(var + 1e-5f);
        S[r] = make_float2(mean, inv);
    }
}

// ---------------------------------------------------------------------------
// fp32 GEMM: C[M x Nn] = act(LN(A) @ W + bias) (+ R)
// Block: 256 threads, tile 64x64, BK=32; each thread computes 4x4.
// ---------------------------------------------------------------------------
__global__ __launch_bounds__(256) void gemm_f32(
    const float* __restrict__ A, const float* __restrict__ W,
    const float* __restrict__ bias, const float* __restrict__ R,
    float* __restrict__ C, int Kd, int Nn, int gelu,
    const float2* __restrict__ lnstats,
    const float* __restrict__ lng, const float* __restrict__ lnb)
{
    __shared__ float As[32][64];   // transposed: As[k][m]
    __shared__ float Ws[32][64];   // Ws[k][n]
    int n0 = blockIdx.x * 64;
    int m0 = blockIdx.y * 64;
    int t  = threadIdx.x;
    int tr = t >> 4, tc = t & 15;
    float acc[4][4] = {};

    for (int k0 = 0; k0 < Kd; k0 += 32) {
        #pragma unroll
        for (int qq = 0; qq < 2; ++qq) {
            int idx = t * 2 + qq;              // 0..511
            int r   = idx >> 3;                // 0..63
            int c4  = idx & 7;                 // 0..7
            float4 av = *(const float4*)&A[(size_t)(m0 + r) * Kd + k0 + c4 * 4];
            if (lnstats) {
                float2 st = lnstats[m0 + r];
                float4 gv = *(const float4*)&lng[k0 + c4 * 4];
                float4 bv = *(const float4*)&lnb[k0 + c4 * 4];
                av.x = (av.x - st.x) * st.y * gv.x + bv.x;
                av.y = (av.y - st.x) * st.y * gv.y + bv.y;
                av.z = (av.z - st.x) * st.y * gv.z + bv.z;
                av.w = (av.w - st.x) * st.y * gv.w + bv.w;
            }
            As[c4 * 4 + 0][r] = av.x;
            As[c4 * 4 + 1][r] = av.y;
            As[c4 * 4 + 2][r] = av.z;
            As[c4 * 4 + 3][r] = av.w;
            int kr  = idx >> 4;                // 0..31
            int nc4 = idx & 15;                // 0..15
            *(float4*)&Ws[kr][nc4 * 4] =
                *(const float4*)&W[(size_t)(k0 + kr) * Nn + n0 + nc4 * 4];
        }
        __syncthreads();
        #pragma unroll
        for (int kk = 0; kk < 32; ++kk) {
            float4 a = *(const float4*)&As[kk][tr * 4];
            float4 b = *(const float4*)&Ws[kk][tc * 4];
            acc[0][0] += a.x * b.x; acc[0][1] += a.x * b.y;
            acc[0][2] += a.x * b.z; acc[0][3] += a.x * b.w;
            acc[1][0] += a.y * b.x; acc[1][1] += a.y * b.y;
            acc[1][2] += a.y * b.z; acc[1][3] += a.y * b.w;
            acc[2][0] += a.z * b.x; acc[2][1] += a.z * b.y;
            acc[2][2] += a.z * b.z; acc[2][3] += a.z * b.w;
            acc[3][0] += a.w * b.x; acc[3][1] += a.w * b.y;
            acc[3][2] += a.w * b.z; acc[3][3] += a.w * b.w;
        }
        __syncthreads();
    }

    float4 bb = *(const float4*)&bias[n0 + tc * 4];
    #pragma unroll
    for (int i = 0; i < 4; ++i) {
        int row = m0 + tr * 4 + i;
        float4 o;
        o.x = acc[i][0] + bb.x;
        o.y = acc[i][1] + bb.y;
        o.z = acc[i][2] + bb.z;
        o.w = acc[i][3] + bb.w;
        if (gelu) {
            o.x = 0.5f * o.x * (1.0f + erff(o.x * 0.70710678118654752f));
            o.y = 0.5f * o.y * (1.0f + erff(o.y * 0.70710678118654752f));
            o.z = 0.5f * o.z * (1.0f + erff(o.z * 0.70710678118654752f));
            o.w = 0.5f * o.w * (1.0f + erff(o.w * 0.70710678118654752f));
        }
        if (R) {
            float4 rv = *(const float4*)&R[(size_t)row * Nn + n0 + tc * 4];
            o.x += rv.x; o.y += rv.y; o.z += rv.z; o.w += rv.w;
        }
        *(float4*)&C[(size_t)row * Nn + n0 + tc * 4] = o;
    }
}

// ---------------------------------------------------------------------------
// Fused top-16 attention, GEMM-style (round 12).
// Block = 256 thr (4 waves) = 64 queries of one (b,h). Per key-tile (64):
// Q,K staged TRANSPOSED in LDS [dim][row] (stride 68); each thread owns a
// 4-query x 4-key score tile: qf = 4-addr broadcast b128, kf = 16-addr
// (2-way aliased = free) b128, 16 fma per dim step — the layout my
// gemm_f32 sustains 79 TF with. No Q broadcast fan-out (rounds 5-11's
// ~1.3ms floor), no big register arrays (round 11's spill).
// Scores bit-identical to rounds 1-11: dim loop runs as 4 PHASES
// (dims ==0,1,2,3 mod 4), reproducing the exact a0..a3 partial chains and
// ((a0+a1)+(a2+a3))*0.125 combine.
// Selection: 16-lane-group ballot-insert (proven rounds 4-9). Each group
// row (trw) holds 4 queries' top-16 lists distributed one-slot-per-lane
// (slotv0..3 by query sub-index i), sorted ascending across tc.
// ---------------------------------------------------------------------------
#define PHASE(POFF)                                                      \
    p0 = p1 = p2 = p3 = make_float4(0.f, 0.f, 0.f, 0.f);                 \
    _Pragma("unroll")                                                    \
    for (int kk = 0; kk < 16; ++kk) {                                    \
        float4 qf = *(const float4*)&Qt[(4 * kk + (POFF)) * LSTR + qcol];\
        float4 kf = *(const float4*)&Kt[(4 * kk + (POFF)) * LSTR + kcol];\
        p0.x = fmaf(qf.x, kf.x, p0.x); p0.y = fmaf(qf.x, kf.y, p0.y);    \
        p0.z = fmaf(qf.x, kf.z, p0.z); p0.w = fmaf(qf.x, kf.w, p0.w);    \
        p1.x = fmaf(qf.y, kf.x, p1.x); p1.y = fmaf(qf.y, kf.y, p1.y);    \
        p1.z = fmaf(qf.y, kf.z, p1.z); p1.w = fmaf(qf.y, kf.w, p1.w);    \
        p2.x = fmaf(qf.z, kf.x, p2.x); p2.y = fmaf(qf.z, kf.y, p2.y);    \
        p2.z = fmaf(qf.z, kf.z, p2.z); p2.w = fmaf(qf.z, kf.w, p2.w);    \
        p3.x = fmaf(qf.w, kf.x, p3.x); p3.y = fmaf(qf.w, kf.y, p3.y);    \
        p3.z = fmaf(qf.w, kf.z, p3.z); p3.w = fmaf(qf.w, kf.w, p3.w);    \
    }

#define SELJ(SV, SI, SCJ, J)                                             \
    {                                                                    \
        float theta = __shfl(SV, gbase);                                 \
        unsigned long long cand = __ballot((SCJ) > theta);               \
        while (cand) {                                                   \
            int src = __ffsll(cand) - 1;                                 \
            cand &= cand - 1;                                            \
            float scb  = __shfl((SCJ), src);                             \
            int   gg   = src >> 4;                                       \
            int   idxb = t0 + ((src & 15) << 2) + (J);                   \
            bool  ing  = (trw == gg);                                    \
            unsigned long long lt = __ballot(SV < scb);                  \
            int cnt = __popcll((lt >> (gg * 16)) & 0xFFFFull);           \
            if (cnt) {                                                   \
                float shv = __shfl(SV, (l + 1) & 63);                    \
                int   shi = __shfl(SI, (l + 1) & 63);                    \
                bool put = ing && (tc == cnt - 1);                       \
                bool shf = ing && (tc < cnt - 1);                        \
                SV = put ? scb : (shf ? shv : SV);                       \
                SI = put ? idxb : (shf ? shi : SI);                      \
            }                                                            \
        }                                                                \
    }

#define SEL(SV, SI, SC)                                                  \
    {                                                                    \
        float theta0 = __shfl(SV, gbase);                                \
        float m3 = fmaxf(fmaxf((SC).x, (SC).y), fmaxf((SC).z, (SC).w));  \
        if (__ballot(m3 > theta0)) {                                     \
            SELJ(SV, SI, (SC).x, 0)                                      \
            SELJ(SV, SI, (SC).y, 1)                                      \
            SELJ(SV, SI, (SC).z, 2)                                      \
            SELJ(SV, SI, (SC).w, 3)                                      \
        }                                                                \
    }

__global__ __launch_bounds__(256, 4) void topk_attn_fused(
    const float* __restrict__ Qm, const float* __restrict__ Km,
    const float* __restrict__ Vm, float* __restrict__ Om)
{
    __shared__ float Qt[64 * LSTR];   // [dim][query], queries 0..63
    __shared__ float Kt[64 * LSTR];   // [dim][key],   keys   0..63

    int bid = blockIdx.x;
    int bh  = bid >> 6;               // 0..15
    int qt  = bid & 63;               // query tile within (b,h)
    int b   = bh >> 3, h = bh & 7;
    int qbase = qt * 64;
    int t   = threadIdx.x;
    int w   = t >> 6;                 // wave 0..3
    int l   = t & 63;
    int trw = l >> 4;                 // query group 0..3
    int tc  = l & 15;                 // key column / slot index
    int gbase = l & 48;               // group base lane
    int qcol = w * 16 + trw * 4;      // this thread's 4 queries (block-local)
    int kcol = tc * 4;                // this thread's 4 keys (tile-local)

    // Stage Q transposed, once.
    #pragma unroll
    for (int qq = 0; qq < 4; ++qq) {
        int idx = t + 256 * qq;       // 0..1023
        int r   = idx >> 4;           // query row 0..63
        int c4  = idx & 15;
        float4 v = *(const float4*)
            &Qm[((size_t)(b * NSEQ + qbase + r)) * DIMD + h * HD + c4 * 4];
        Qt[(c4 * 4 + 0) * LSTR + r] = v.x;
        Qt[(c4 * 4 + 1) * LSTR + r] = v.y;
        Qt[(c4 * 4 + 2) * LSTR + r] = v.z;
        Qt[(c4 * 4 + 3) * LSTR + r] = v.w;
    }

    float slotv0 = -INFINITY, slotv1 = -INFINITY,
          slotv2 = -INFINITY, slotv3 = -INFINITY;
    int   sloti0 = 0, sloti1 = 0, sloti2 = 0, sloti3 = 0;

    for (int t0 = 0; t0 < NSEQ; t0 += 64) {
        __syncthreads();              // covers Q stage (iter 0) + prior reads
        #pragma unroll
        for (int qq = 0; qq < 4; ++qq) {
            int idx = t + 256 * qq;
            int r   = idx >> 4;       // key row 0..63
            int c4  = idx & 15;
            float4 v = *(const float4*)
                &Km[((size_t)(b * NSEQ + t0 + r)) * DIMD + h * HD + c4 * 4];
            Kt[(c4 * 4 + 0) * LSTR + r] = v.x;
            Kt[(c4 * 4 + 1) * LSTR + r] = v.y;
            Kt[(c4 * 4 + 2) * LSTR + r] = v.z;
            Kt[(c4 * 4 + 3) * LSTR + r] = v.w;
        }
        __syncthreads();

        float4 p0, p1, p2, p3, c0, c1, c2, c3, d0, d1, d2, d3;
        PHASE(0)                      // a0: dims 0,4,..,60
        c0 = p0; c1 = p1; c2 = p2; c3 = p3;
        PHASE(1)                      // a1
        c0.x += p0.x; c0.y += p0.y; c0.z += p0.z; c0.w += p0.w;
        c1.x += p1.x; c1.y += p1.y; c1.z += p1.z; c1.w += p1.w;
        c2.x += p2.x; c2.y += p2.y; c2.z += p2.z; c2.w += p2.w;
        c3.x += p3.x; c3.y += p3.y; c3.z += p3.z; c3.w += p3.w;
        PHASE(2)                      // a2
        d0 = p0; d1 = p1; d2 = p2; d3 = p3;
        PHASE(3)                      // a3
        d0.x += p0.x; d0.y += p0.y; d0.z += p0.z; d0.w += p0.w;
        d1.x += p1.x; d1.y += p1.y; d1.z += p1.z; d1.w += p1.w;
        d2.x += p2.x; d2.y += p2.y; d2.z += p2.z; d2.w += p2.w;
        d3.x += p3.x; d3.y += p3.y; d3.z += p3.z; d3.w += p3.w;
        float4 s0, s1, s2, s3;        // ((a0+a1)+(a2+a3))*0.125, exact order
        s0.x = (c0.x + d0.x) * 0.125f; s0.y = (c0.y + d0.y) * 0.125f;
        s0.z = (c0.z + d0.z) * 0.125f; s0.w = (c0.w + d0.w) * 0.125f;
        s1.x = (c1.x + d1.x) * 0.125f; s1.y = (c1.y + d1.y) * 0.125f;
        s1.z = (c1.z + d1.z) * 0.125f; s1.w = (c1.w + d1.w) * 0.125f;
        s2.x = (c2.x + d2.x) * 0.125f; s2.y = (c2.y + d2.y) * 0.125f;
        s2.z = (c2.z + d2.z) * 0.125f; s2.w = (c2.w + d2.w) * 0.125f;
        s3.x = (c3.x + d3.x) * 0.125f; s3.y = (c3.y + d3.y) * 0.125f;
        s3.z = (c3.z + d3.z) * 0.125f; s3.w = (c3.w + d3.w) * 0.125f;

        SEL(slotv0, sloti0, s0)
        SEL(slotv1, sloti1, s1)
        SEL(slotv2, sloti2, s2)
        SEL(slotv3, sloti3, s3)
    }

    // ---- softmax weights per query (group-local), then V-gather ----
    float wn0, wn1, wn2, wn3;
    {
        float mx, wv, ssum;
        #define SMAX(SV, WN)                                             \
            mx = __shfl(SV, gbase + 15);                                 \
            wv = expf(SV - mx);                                          \
            ssum = wv;                                                   \
            ssum += __shfl_xor(ssum, 1);                                 \
            ssum += __shfl_xor(ssum, 2);                                 \
            ssum += __shfl_xor(ssum, 4);                                 \
            ssum += __shfl_xor(ssum, 8);                                 \
            WN = wv * (1.0f / ssum);
        SMAX(slotv0, wn0) SMAX(slotv1, wn1) SMAX(slotv2, wn2) SMAX(slotv3, wn3)
        #undef SMAX
    }

    const float* vb = Vm + ((size_t)b * NSEQ) * DIMD + h * HD + l;
    float* ob = Om + ((size_t)(b * NSEQ + qbase + w * 16)) * DIMD + h * HD + l;
    #pragma unroll
    for (int q16 = 0; q16 < 16; ++q16) {
        int tq = q16 >> 2;            // source group
        float acc = 0.f;
        #pragma unroll
        for (int sidx = 15; sidx >= 0; --sidx) {   // descending = ref order
            float wi; int ki;
            switch (q16 & 3) {
                case 0: wi = __shfl(wn0, tq * 16 + sidx);
                        ki = __shfl(sloti0, tq * 16 + sidx); break;
                case 1: wi = __shfl(wn1, tq * 16 + sidx);
                        ki = __shfl(sloti1, tq * 16 + sidx); break;
                case 2: wi = __shfl(wn2, tq * 16 + sidx);
                        ki = __shfl(sloti2, tq * 16 + sidx); break;
                default: wi = __shfl(wn3, tq * 16 + sidx);
                        ki = __shfl(sloti3, tq * 16 + sidx); break;
            }
            acc = fmaf(wi, vb[(size_t)ki * DIMD], acc);
        }
        ob[(size_t)q16 * DIMD] = acc;
    }
}

// ---------------------------------------------------------------------------
extern "C" void kernel_launch(void* const* d_in, const int* in_sizes, int n_in,
                              void* d_out, int out_size, void* d_ws, size_t ws_size,
                              hipStream_t stream)
{
    (void)in_sizes; (void)n_in; (void)out_size; (void)ws_size;
    const float* x    = (const float*)d_in[0];
    const float* q_w  = (const float*)d_in[1];
    const float* q_b  = (const float*)d_in[2];
    const float* k_w  = (const float*)d_in[3];
    const float* k_b  = (const float*)d_in[4];
    const float* v_w  = (const float*)d_in[5];
    const float* v_b  = (const float*)d_in[6];
    const float* o_w  = (const float*)d_in[7];
    const float* o_b  = (const float*)d_in[8];
    const float* ln1g = (const float*)d_in[9];
    const float* ln1b = (const float*)d_in[10];
    const float* ln2g = (const float*)d_in[11];
    const float* ln2b = (const float*)d_in[12];
    const float* ff1w = (const float*)d_in[13];
    const float* ff1b = (const float*)d_in[14];
    const float* ff2w = (const float*)d_in[15];
    const float* ff2b = (const float*)d_in[16];
    float* out = (float*)d_out;
    float* ws  = (float*)d_ws;

    const size_t SZ = (size_t)8192 * DIMD;   // 4M floats = 16 MiB
    float*  Qb      = ws;                    // [8192 x 512]
    float*  Kb      = ws + SZ;
    float*  Vb      = ws + 2 * SZ;
    float*  attnOut = ws + 3 * SZ;           // [8192 x 512]
    float2* stats   = (float2*)(ws + 4 * SZ);
    float*  ffb     = ws;                    // [8192 x 2048], reuses ws

    dim3 g512(8, 128);    // Nn/64, M/64

    // LN1 stats, then Q/K/V projections with LN fused into the A-load.
    ln_stats_kernel<<<8192, 256, 0, stream>>>(x, stats);
    gemm_f32<<<g512, 256, 0, stream>>>(x, q_w, q_b, nullptr, Qb,
                                       512, 512, 0, stats, ln1g, ln1b);
    gemm_f32<<<g512, 256, 0, stream>>>(x, k_w, k_b, nullptr, Kb,
                                       512, 512, 0, stats, ln1g, ln1b);
    gemm_f32<<<g512, 256, 0, stream>>>(x, v_w, v_b, nullptr, Vb,
                                       512, 512, 0, stats, ln1g, ln1b);

    // Fused top-16 attention (GEMM layout, 4-phase exact-order scores).
    topk_attn_fused<<<1024, 256, 0, stream>>>(Qb, Kb, Vb, attnOut);

    // x2 = x + attnOut @ o_w + o_b   -> d_out
    gemm_f32<<<g512, 256, 0, stream>>>(attnOut, o_w, o_b, x, out,
                                       512, 512, 0, nullptr, nullptr, nullptr);

    // LN2 stats from x2, FFN with LN fused; ff1 -> ffb (gelu), then
    // out = x2 + ffb @ ff2_w + ff2_b (in-place residual on d_out).
    ln_stats_kernel<<<8192, 256, 0, stream>>>(out, stats);
    gemm_f32<<<dim3(32, 128), 256, 0, stream>>>(out, ff1w, ff1b, nullptr, ffb,
                                                512, 2048, 1, stats, ln2g, ln2b);
    gemm_f32<<<g512, 256, 0, stream>>>(ffb, ff2w, ff2b, out, out,
                                       2048, 512, 0, nullptr, nullptr, nullptr);
}

// Round 13
// 6888.329 us; speedup vs baseline: 5.5595x; 5.5595x over previous
//
#include <hip/hip_runtime.h>
#include <math.h>

#define DIMD 512
#define NSEQ 4096
#define NHEAD 8
#define HD 64
#define TOPK 16
#define QSTR 68   // Qt/Kt row stride (floats): 272B, 16B-aligned
#define SSTR 69   // score buffer row stride

// ---------------------------------------------------------------------------
// Per-row LayerNorm stats: mean and 1/sqrt(var+eps). One block per row.
// ---------------------------------------------------------------------------
__global__ __launch_bounds__(256) void ln_stats_kernel(
    const float* __restrict__ X, float2* __restrict__ S)
{
    int r = blockIdx.x;
    int t = threadIdx.x;
    const float* xr = X + (size_t)r * DIMD;
    float a = xr[t], b = xr[t + 256];
    float s = a + b;
    float sq = a * a + b * b;
    #pragma unroll
    for (int off = 32; off > 0; off >>= 1) {
        s  += __shfl_down(s, off, 64);
        sq += __shfl_down(sq, off, 64);
    }
    __shared__ float red[8];
    int wv = t >> 6, ln = t & 63;
    if (ln == 0) { red[wv] = s; red[wv + 4] = sq; }
    __syncthreads();
    if (t == 0) {
        float st  = red[0] + red[1] + red[2] + red[3];
        float sqt = red[4] + red[5] + red[6] + red[7];
        float mean = st * (1.0f / DIMD);
        float var  = sqt * (1.0f / DIMD) - mean * mean;
        float inv  = 1.0f / sqrtf(var + 1e-5f);
        S[r] = make_float2(mean, inv);
    }
}

// ---------------------------------------------------------------------------
// fp32 GEMM: C[M x Nn] = act(LN(A) @ W + bias) (+ R)
// Block: 256 threads, tile 64x64, BK=32; each thread computes 4x4.
// ---------------------------------------------------------------------------
__global__ __launch_bounds__(256) void gemm_f32(
    const float* __restrict__ A, const float* __restrict__ W,
    const float* __restrict__ bias, const float* __restrict__ R,
    float* __restrict__ C, int Kd, int Nn, int gelu,
    const float2* __restrict__ lnstats,
    const float* __restrict__ lng, const float* __restrict__ lnb)
{
    __shared__ float As[32][64];   // transposed: As[k][m]
    __shared__ float Ws[32][64];   // Ws[k][n]
    int n0 = blockIdx.x * 64;
    int m0 = blockIdx.y * 64;
    int t  = threadIdx.x;
    int tr = t >> 4, tc = t & 15;
    float acc[4][4] = {};

    for (int k0 = 0; k0 < Kd; k0 += 32) {
        #pragma unroll
        for (int qq = 0; qq < 2; ++qq) {
            int idx = t * 2 + qq;              // 0..511
            int r   = idx >> 3;                // 0..63
            int c4  = idx & 7;                 // 0..7
            float4 av = *(const float4*)&A[(size_t)(m0 + r) * Kd + k0 + c4 * 4];
            if (lnstats) {
                float2 st = lnstats[m0 + r];
                float4 gv = *(const float4*)&lng[k0 + c4 * 4];
                float4 bv = *(const float4*)&lnb[k0 + c4 * 4];
                av.x = (av.x - st.x) * st.y * gv.x + bv.x;
                av.y = (av.y - st.x) * st.y * gv.y + bv.y;
                av.z = (av.z - st.x) * st.y * gv.z + bv.z;
                av.w = (av.w - st.x) * st.y * gv.w + bv.w;
            }
            As[c4 * 4 + 0][r] = av.x;
            As[c4 * 4 + 1][r] = av.y;
            As[c4 * 4 + 2][r] = av.z;
            As[c4 * 4 + 3][r] = av.w;
            int kr  = idx >> 4;                // 0..31
            int nc4 = idx & 15;                // 0..15
            *(float4*)&Ws[kr][nc4 * 4] =
                *(const float4*)&W[(size_t)(k0 + kr) * Nn + n0 + nc4 * 4];
        }
        __syncthreads();
        #pragma unroll
        for (int kk = 0; kk < 32; ++kk) {
            float4 a = *(const float4*)&As[kk][tr * 4];
            float4 b = *(const float4*)&Ws[kk][tc * 4];
            acc[0][0] += a.x * b.x; acc[0][1] += a.x * b.y;
            acc[0][2] += a.x * b.z; acc[0][3] += a.x * b.w;
            acc[1][0] += a.y * b.x; acc[1][1] += a.y * b.y;
            acc[1][2] += a.y * b.z; acc[1][3] += a.y * b.w;
            acc[2][0] += a.z * b.x; acc[2][1] += a.z * b.y;
            acc[2][2] += a.z * b.z; acc[2][3] += a.z * b.w;
            acc[3][0] += a.w * b.x; acc[3][1] += a.w * b.y;
            acc[3][2] += a.w * b.z; acc[3][3] += a.w * b.w;
        }
        __syncthreads();
    }

    float4 bb = *(const float4*)&bias[n0 + tc * 4];
    #pragma unroll
    for (int i = 0; i < 4; ++i) {
        int row = m0 + tr * 4 + i;
        float4 o;
        o.x = acc[i][0] + bb.x;
        o.y = acc[i][1] + bb.y;
        o.z = acc[i][2] + bb.z;
        o.w = acc[i][3] + bb.w;
        if (gelu) {
            o.x = 0.5f * o.x * (1.0f + erff(o.x * 0.70710678118654752f));
            o.y = 0.5f * o.y * (1.0f + erff(o.y * 0.70710678118654752f));
            o.z = 0.5f * o.z * (1.0f + erff(o.z * 0.70710678118654752f));
            o.w = 0.5f * o.w * (1.0f + erff(o.w * 0.70710678118654752f));
        }
        if (R) {
            float4 rv = *(const float4*)&R[(size_t)row * Nn + n0 + tc * 4];
            o.x += rv.x; o.y += rv.y; o.z += rv.z; o.w += rv.w;
        }
        *(float4*)&C[(size_t)row * Nn + n0 + tc * 4] = o;
    }
}

// ---------------------------------------------------------------------------
// Fused top-16 attention, round 13: GEMM scores -> LDS -> ballot select.
// Block = 256 thr (4 waves) = 64 queries of one (b,h). Per 64-key tile:
//  1) GEMM phase (round-12 structure, bit-exact 4-phase partial sums):
//     each thread computes a 4-query x 4-key score tile and WRITES IT TO
//     LDS Sc[64][69]; p/c/d regs die immediately (round 11/12 lesson:
//     shfl-ing GEMM results through divergent select loops forces 64+
//     regs live across uncoalescable ranges -> scratch spill, 90GB FETCH).
//  2) barrier; selection phase: each wave processes its own 16 queries
//     with the round-5 ballot-insert (lane=key, sc from conflict-free
//     ds_read_b32); lists in 4 register sets x 4 lane-groups.
// Candidate order (ascending keys, ascending tiles), score arithmetic,
// softmax and gather order bit-identical to rounds 1-12.
// ---------------------------------------------------------------------------
#define PHASE(POFF)                                                      \
    p0 = p1 = p2 = p3 = make_float4(0.f, 0.f, 0.f, 0.f);                 \
    _Pragma("unroll")                                                    \
    for (int kk = 0; kk < 16; ++kk) {                                    \
        float4 qf = *(const float4*)&Qt[(4 * kk + (POFF)) * QSTR + qcol];\
        float4 kf = *(const float4*)&Kt[(4 * kk + (POFF)) * QSTR + kcol];\
        p0.x = fmaf(qf.x, kf.x, p0.x); p0.y = fmaf(qf.x, kf.y, p0.y);    \
        p0.z = fmaf(qf.x, kf.z, p0.z); p0.w = fmaf(qf.x, kf.w, p0.w);    \
        p1.x = fmaf(qf.y, kf.x, p1.x); p1.y = fmaf(qf.y, kf.y, p1.y);    \
        p1.z = fmaf(qf.y, kf.z, p1.z); p1.w = fmaf(qf.y, kf.w, p1.w);    \
        p2.x = fmaf(qf.z, kf.x, p2.x); p2.y = fmaf(qf.z, kf.y, p2.y);    \
        p2.z = fmaf(qf.z, kf.z, p2.z); p2.w = fmaf(qf.z, kf.w, p2.w);    \
        p3.x = fmaf(qf.w, kf.x, p3.x); p3.y = fmaf(qf.w, kf.y, p3.y);    \
        p3.z = fmaf(qf.w, kf.z, p3.z); p3.w = fmaf(qf.w, kf.w, p3.w);    \
    }

#define SEL_ONE(SV, SI, GG)                                              \
    {                                                                    \
        float theta = __shfl(SV, (GG) * 16);                             \
        unsigned long long cand = __ballot(sc > theta);                  \
        while (cand) {                                                   \
            int src = __ffsll(cand) - 1;                                 \
            cand &= cand - 1;                                            \
            float scb = __shfl(sc, src);                                 \
            int idxb = t0 + src;                                         \
            unsigned long long lt = __ballot(SV < scb);                  \
            int cnt = __popcll((lt >> ((GG) * 16)) & 0xFFFFull);         \
            if (cnt) {                                                   \
                float shv = __shfl(SV, (l + 1) & 63);                    \
                int   shi = __shfl(SI, (l + 1) & 63);                    \
                bool ing = (trw == (GG));                                \
                bool put = ing && (tc == cnt - 1);                       \
                bool shf = ing && (tc < cnt - 1);                        \
                SV = put ? scb : (shf ? shv : SV);                       \
                SI = put ? idxb : (shf ? shi : SI);                      \
            }                                                            \
        }                                                                \
    }

__global__ __launch_bounds__(256, 3) void topk_attn_fused(
    const float* __restrict__ Qm, const float* __restrict__ Km,
    const float* __restrict__ Vm, float* __restrict__ Om)
{
    __shared__ float Qt[64 * QSTR];   // [dim][query]
    __shared__ float Kt[64 * QSTR];   // [dim][key]
    __shared__ float Sc[64 * SSTR];   // [query][key] scores

    int bid = blockIdx.x;
    int bh  = bid >> 6;               // 0..15
    int qt  = bid & 63;               // query tile within (b,h)
    int b   = bh >> 3, h = bh & 7;
    int qbase = qt * 64;
    int t   = threadIdx.x;
    int w   = t >> 6;                 // wave 0..3
    int l   = t & 63;
    int trw = l >> 4;                 // 0..3
    int tc  = l & 15;                 // 0..15
    int qcol = w * 16 + trw * 4;      // this thread's 4 queries (block-local)
    int kcol = tc * 4;                // this thread's 4 keys (tile-local)

    // Stage Q transposed, once.
    #pragma unroll
    for (int qq = 0; qq < 4; ++qq) {
        int idx = t + 256 * qq;       // 0..1023
        int r   = idx >> 4;           // query row 0..63
        int c4  = idx & 15;
        float4 v = *(const float4*)
            &Qm[((size_t)(b * NSEQ + qbase + r)) * DIMD + h * HD + c4 * 4];
        Qt[(c4 * 4 + 0) * QSTR + r] = v.x;
        Qt[(c4 * 4 + 1) * QSTR + r] = v.y;
        Qt[(c4 * 4 + 2) * QSTR + r] = v.z;
        Qt[(c4 * 4 + 3) * QSTR + r] = v.w;
    }

    float slotv0 = -INFINITY, slotv1 = -INFINITY,
          slotv2 = -INFINITY, slotv3 = -INFINITY;
    int   sloti0 = 0, sloti1 = 0, sloti2 = 0, sloti3 = 0;

    for (int t0 = 0; t0 < NSEQ; t0 += 64) {
        __syncthreads();              // Kt/Sc safe to overwrite
        #pragma unroll
        for (int qq = 0; qq < 4; ++qq) {
            int idx = t + 256 * qq;
            int r   = idx >> 4;       // key row 0..63
            int c4  = idx & 15;
            float4 v = *(const float4*)
                &Km[((size_t)(b * NSEQ + t0 + r)) * DIMD + h * HD + c4 * 4];
            Kt[(c4 * 4 + 0) * QSTR + r] = v.x;
            Kt[(c4 * 4 + 1) * QSTR + r] = v.y;
            Kt[(c4 * 4 + 2) * QSTR + r] = v.z;
            Kt[(c4 * 4 + 3) * QSTR + r] = v.w;
        }
        __syncthreads();

        // ---- GEMM phase: 4x4 scores, bit-exact 4-phase partials ----
        {
            float4 p0, p1, p2, p3, c0, c1, c2, c3, d0, d1, d2, d3;
            PHASE(0)                  // a0: dims 0,4,..,60
            c0 = p0; c1 = p1; c2 = p2; c3 = p3;
            PHASE(1)                  // a1
            c0.x += p0.x; c0.y += p0.y; c0.z += p0.z; c0.w += p0.w;
            c1.x += p1.x; c1.y += p1.y; c1.z += p1.z; c1.w += p1.w;
            c2.x += p2.x; c2.y += p2.y; c2.z += p2.z; c2.w += p2.w;
            c3.x += p3.x; c3.y += p3.y; c3.z += p3.z; c3.w += p3.w;
            PHASE(2)                  // a2
            d0 = p0; d1 = p1; d2 = p2; d3 = p3;
            PHASE(3)                  // a3
            d0.x += p0.x; d0.y += p0.y; d0.z += p0.z; d0.w += p0.w;
            d1.x += p1.x; d1.y += p1.y; d1.z += p1.z; d1.w += p1.w;
            d2.x += p2.x; d2.y += p2.y; d2.z += p2.z; d2.w += p2.w;
            d3.x += p3.x; d3.y += p3.y; d3.z += p3.z; d3.w += p3.w;
            float4 s;                 // ((a0+a1)+(a2+a3))*0.125, exact order
            s.x = (c0.x + d0.x) * 0.125f; s.y = (c0.y + d0.y) * 0.125f;
            s.z = (c0.z + d0.z) * 0.125f; s.w = (c0.w + d0.w) * 0.125f;
            *(float4*)&Sc[(qcol + 0) * SSTR + kcol] = s;
            s.x = (c1.x + d1.x) * 0.125f; s.y = (c1.y + d1.y) * 0.125f;
            s.z = (c1.z + d1.z) * 0.125f; s.w = (c1.w + d1.w) * 0.125f;
            *(float4*)&Sc[(qcol + 1) * SSTR + kcol] = s;
            s.x = (c2.x + d2.x) * 0.125f; s.y = (c2.y + d2.y) * 0.125f;
            s.z = (c2.z + d2.z) * 0.125f; s.w = (c2.w + d2.w) * 0.125f;
            *(float4*)&Sc[(qcol + 2) * SSTR + kcol] = s;
            s.x = (c3.x + d3.x) * 0.125f; s.y = (c3.y + d3.y) * 0.125f;
            s.z = (c3.z + d3.z) * 0.125f; s.w = (c3.w + d3.w) * 0.125f;
            *(float4*)&Sc[(qcol + 3) * SSTR + kcol] = s;
        }
        __syncthreads();

        // ---- selection phase: this wave's 16 queries, lane = key ----
        #pragma unroll
        for (int jq = 0; jq < 16; ++jq) {
            float sc = Sc[(w * 16 + jq) * SSTR + l];
            switch (jq >> 2) {
                case 0: SEL_ONE(slotv0, sloti0, (jq & 3)) break;
                case 1: SEL_ONE(slotv1, sloti1, (jq & 3)) break;
                case 2: SEL_ONE(slotv2, sloti2, (jq & 3)) break;
                default: SEL_ONE(slotv3, sloti3, (jq & 3)) break;
            }
        }
    }

    // ---- softmax weights (per set, group-local), then V-gather ----
    float wn0, wn1, wn2, wn3;
    {
        float mx, wv, ssum;
        #define SMAX(SV, WN)                                             \
            mx = __shfl(SV, (l & 48) + 15);                              \
            wv = expf(SV - mx);                                          \
            ssum = wv;                                                   \
            ssum += __shfl_xor(ssum, 1);                                 \
            ssum += __shfl_xor(ssum, 2);                                 \
            ssum += __shfl_xor(ssum, 4);                                 \
            ssum += __shfl_xor(ssum, 8);                                 \
            WN = wv * (1.0f / ssum);
        SMAX(slotv0, wn0) SMAX(slotv1, wn1) SMAX(slotv2, wn2) SMAX(slotv3, wn3)
        #undef SMAX
    }

    const float* vb = Vm + ((size_t)b * NSEQ) * DIMD + h * HD + l;
    float* ob = Om + ((size_t)(b * NSEQ + qbase + w * 16)) * DIMD + h * HD + l;
    #pragma unroll
    for (int jq = 0; jq < 16; ++jq) {
        int gg = jq & 3;
        float acc = 0.f;
        #pragma unroll
        for (int sidx = 15; sidx >= 0; --sidx) {   // descending = ref order
            float wi; int ki;
            switch (jq >> 2) {
                case 0: wi = __shfl(wn0, gg * 16 + sidx);
                        ki = __shfl(sloti0, gg * 16 + sidx); break;
                case 1: wi = __shfl(wn1, gg * 16 + sidx);
                        ki = __shfl(sloti1, gg * 16 + sidx); break;
                case 2: wi = __shfl(wn2, gg * 16 + sidx);
                        ki = __shfl(sloti2, gg * 16 + sidx); break;
                default: wi = __shfl(wn3, gg * 16 + sidx);
                        ki = __shfl(sloti3, gg * 16 + sidx); break;
            }
            acc = fmaf(wi, vb[(size_t)ki * DIMD], acc);
        }
        ob[(size_t)jq * DIMD] = acc;
    }
}

// ---------------------------------------------------------------------------
extern "C" void kernel_launch(void* const* d_in, const int* in_sizes, int n_in,
                              void* d_out, int out_size, void* d_ws, size_t ws_size,
                              hipStream_t stream)
{
    (void)in_sizes; (void)n_in; (void)out_size; (void)ws_size;
    const float* x    = (const float*)d_in[0];
    const float* q_w  = (const float*)d_in[1];
    const float* q_b  = (const float*)d_in[2];
    const float* k_w  = (const float*)d_in[3];
    const float* k_b  = (const float*)d_in[4];
    const float* v_w  = (const float*)d_in[5];
    const float* v_b  = (const float*)d_in[6];
    const float* o_w  = (const float*)d_in[7];
    const float* o_b  = (const float*)d_in[8];
    const float* ln1g = (const float*)d_in[9];
    const float* ln1b = (const float*)d_in[10];
    const float* ln2g = (const float*)d_in[11];
    const float* ln2b = (const float*)d_in[12];
    const float* ff1w = (const float*)d_in[13];
    const float* ff1b = (const float*)d_in[14];
    const float* ff2w = (const float*)d_in[15];
    const float* ff2b = (const float*)d_in[16];
    float* out = (float*)d_out;
    float* ws  = (float*)d_ws;

    const size_t SZ = (size_t)8192 * DIMD;   // 4M floats = 16 MiB
    float*  Qb      = ws;                    // [8192 x 512]
    float*  Kb      = ws + SZ;
    float*  Vb      = ws + 2 * SZ;
    float*  attnOut = ws + 3 * SZ;           // [8192 x 512]
    float2* stats   = (float2*)(ws + 4 * SZ);
    float*  ffb     = ws;                    // [8192 x 2048], reuses ws

    dim3 g512(8, 128);    // Nn/64, M/64

    // LN1 stats, then Q/K/V projections with LN fused into the A-load.
    ln_stats_kernel<<<8192, 256, 0, stream>>>(x, stats);
    gemm_f32<<<g512, 256, 0, stream>>>(x, q_w, q_b, nullptr, Qb,
                                       512, 512, 0, stats, ln1g, ln1b);
    gemm_f32<<<g512, 256, 0, stream>>>(x, k_w, k_b, nullptr, Kb,
                                       512, 512, 0, stats, ln1g, ln1b);
    gemm_f32<<<g512, 256, 0, stream>>>(x, v_w, v_b, nullptr, Vb,
                                       512, 512, 0, stats, ln1g, ln1b);

    // Fused top-16 attention (GEMM scores -> LDS -> ballot select).
    topk_attn_fused<<<1024, 256, 0, stream>>>(Qb, Kb, Vb, attnOut);

    // x2 = x + attnOut @ o_w + o_b   -> d_out
    gemm_f32<<<g512, 256, 0, stream>>>(attnOut, o_w, o_b, x, out,
                                       512, 512, 0, nullptr, nullptr, nullptr);

    // LN2 stats from x2, FFN with LN fused; ff1 -> ffb (gelu), then
    // out = x2 + ffb @ ff2_w + ff2_b (in-place residual on d_out).
    ln_stats_kernel<<<8192, 256, 0, stream>>>(out, stats);
    gemm_f32<<<dim3(32, 128), 256, 0, stream>>>(out, ff1w, ff1b, nullptr, ffb,
                                                512, 2048, 1, stats, ln2g, ln2b);
    gemm_f32<<<g512, 256, 0, stream>>>(ffb, ff2w, ff2b, out, out,
                                       2048, 512, 0, nullptr, nullptr, nullptr);
}